// Round 1
// baseline (2264.989 us; speedup 1.0000x reference)
//
#include <hip/hip_runtime.h>
#include <math.h>

// Problem constants
constexpr int Bb  = 2;
constexpr int Ss  = 2048;
constexpr int Dd  = 1024;
constexpr int Hh  = 16;
constexpr int Dh  = 64;
constexpr int BS  = Bb * Ss;                 // 4096 rows
constexpr long long QKV = (long long)Bb * Hh * Ss * Dh;  // 4194304 elems
constexpr float SCALE = 0.125f;              // 1/sqrt(64)
constexpr float EPSV  = 1e-6f;

// ---------------------------------------------------------------------------
// GEMM: Y[m,e] = sum_k X[m,k] * W[e,k] + bias[e], written to [B,H,S,Dh] layout
// X: [4096, 1024], W: [1024, 1024] row-major (so B^T-style: k contiguous both)
// grid (D/64=16, BS/64=64), block (16,16); each thread 4x4 accum
// ---------------------------------------------------------------------------
__global__ __launch_bounds__(256)
void proj_qkv_kernel(const float* __restrict__ X, const float* __restrict__ W,
                     const float* __restrict__ bias, float* __restrict__ out)
{
    __shared__ float As[64][33];
    __shared__ float Bs[64][33];
    const int tx = threadIdx.x, ty = threadIdx.y;
    const int tid = ty * 16 + tx;
    const int m0 = blockIdx.y * 64;
    const int n0 = blockIdx.x * 64;
    float acc[4][4] = {};
    for (int k0 = 0; k0 < Dd; k0 += 32) {
#pragma unroll
        for (int l = 0; l < 8; ++l) {
            int idx = l * 256 + tid;
            int r = idx >> 5, c = idx & 31;
            As[r][c] = X[(size_t)(m0 + r) * Dd + k0 + c];
            Bs[r][c] = W[(size_t)(n0 + r) * Dd + k0 + c];
        }
        __syncthreads();
#pragma unroll
        for (int kk = 0; kk < 32; ++kk) {
            float a[4], b[4];
#pragma unroll
            for (int i = 0; i < 4; ++i) a[i] = As[ty * 4 + i][kk];
#pragma unroll
            for (int j = 0; j < 4; ++j) b[j] = Bs[tx * 4 + j][kk];
#pragma unroll
            for (int i = 0; i < 4; ++i)
#pragma unroll
                for (int j = 0; j < 4; ++j)
                    acc[i][j] += a[i] * b[j];
        }
        __syncthreads();
    }
#pragma unroll
    for (int i = 0; i < 4; ++i) {
        int m = m0 + ty * 4 + i;
        int b = m >> 11, s = m & 2047;      // S = 2048
#pragma unroll
        for (int j = 0; j < 4; ++j) {
            int e = n0 + tx * 4 + j;
            int h = e >> 6, dh = e & 63;    // Dh = 64
            out[(((size_t)(b * Hh + h)) * Ss + s) * Dh + dh] = acc[i][j] + bias[e];
        }
    }
}

// ---------------------------------------------------------------------------
// Output projection: Y[m,n] = sum_k A[m,k] * Wo[n,k] + bo[n] + Res[m,n]
// ---------------------------------------------------------------------------
__global__ __launch_bounds__(256)
void outproj_kernel(const float* __restrict__ X, const float* __restrict__ W,
                    const float* __restrict__ bias, const float* __restrict__ res,
                    float* __restrict__ out)
{
    __shared__ float As[64][33];
    __shared__ float Bs[64][33];
    const int tx = threadIdx.x, ty = threadIdx.y;
    const int tid = ty * 16 + tx;
    const int m0 = blockIdx.y * 64;
    const int n0 = blockIdx.x * 64;
    float acc[4][4] = {};
    for (int k0 = 0; k0 < Dd; k0 += 32) {
#pragma unroll
        for (int l = 0; l < 8; ++l) {
            int idx = l * 256 + tid;
            int r = idx >> 5, c = idx & 31;
            As[r][c] = X[(size_t)(m0 + r) * Dd + k0 + c];
            Bs[r][c] = W[(size_t)(n0 + r) * Dd + k0 + c];
        }
        __syncthreads();
#pragma unroll
        for (int kk = 0; kk < 32; ++kk) {
            float a[4], b[4];
#pragma unroll
            for (int i = 0; i < 4; ++i) a[i] = As[ty * 4 + i][kk];
#pragma unroll
            for (int j = 0; j < 4; ++j) b[j] = Bs[tx * 4 + j][kk];
#pragma unroll
            for (int i = 0; i < 4; ++i)
#pragma unroll
                for (int j = 0; j < 4; ++j)
                    acc[i][j] += a[i] * b[j];
        }
        __syncthreads();
    }
#pragma unroll
    for (int i = 0; i < 4; ++i) {
        size_t m = m0 + ty * 4 + i;
#pragma unroll
        for (int j = 0; j < 4; ++j) {
            size_t n = n0 + tx * 4 + j;
            out[m * Dd + n] = acc[i][j] + bias[n] + res[m * Dd + n];
        }
    }
}

// ---------------------------------------------------------------------------
// Scores: S[bh, i, j] = (1/8) * sum_d q[bh,i,d] * k[bh,j,d]
// grid (Ntiles=32, Mtiles=32, BH=32), block (16,16). K=64 single pass.
// ---------------------------------------------------------------------------
__global__ __launch_bounds__(256)
void scores_kernel(const float* __restrict__ q, const float* __restrict__ k,
                   float* __restrict__ scores)
{
    __shared__ float As[64][65];
    __shared__ float Bs[64][65];
    const int tx = threadIdx.x, ty = threadIdx.y;
    const int tid = ty * 16 + tx;
    const int bh = blockIdx.z;
    const int m0 = blockIdx.y * 64;
    const int n0 = blockIdx.x * 64;
    const float* qb = q + (size_t)bh * Ss * Dh;
    const float* kb = k + (size_t)bh * Ss * Dh;
#pragma unroll
    for (int l = 0; l < 16; ++l) {
        int idx = l * 256 + tid;
        int r = idx >> 6, c = idx & 63;
        As[r][c] = qb[(size_t)(m0 + r) * Dh + c];
        Bs[r][c] = kb[(size_t)(n0 + r) * Dh + c];
    }
    __syncthreads();
    float acc[4][4] = {};
#pragma unroll
    for (int kk = 0; kk < 64; ++kk) {
        float a[4], b[4];
#pragma unroll
        for (int i = 0; i < 4; ++i) a[i] = As[ty * 4 + i][kk];
#pragma unroll
        for (int j = 0; j < 4; ++j) b[j] = Bs[tx * 4 + j][kk];
#pragma unroll
        for (int i = 0; i < 4; ++i)
#pragma unroll
            for (int j = 0; j < 4; ++j)
                acc[i][j] += a[i] * b[j];
    }
    float* sb = scores + (size_t)bh * Ss * Ss;
#pragma unroll
    for (int i = 0; i < 4; ++i)
#pragma unroll
        for (int j = 0; j < 4; ++j)
            sb[(size_t)(m0 + ty * 4 + i) * Ss + (n0 + tx * 4 + j)] = acc[i][j] * SCALE;
}

// ---------------------------------------------------------------------------
// In-place row softmax over rows of length 2048. One block per row.
// Each thread holds 8 elements (two float4 stripes) in registers.
// ---------------------------------------------------------------------------
__global__ __launch_bounds__(256)
void softmax_kernel(float* __restrict__ scores)
{
    __shared__ float sm[4];
    const size_t row = blockIdx.x;
    float4* rp = (float4*)(scores + row * 2048);
    const int t = threadIdx.x;
    float4 f0 = rp[t];
    float4 f1 = rp[t + 256];

    float m = fmaxf(fmaxf(fmaxf(f0.x, f0.y), fmaxf(f0.z, f0.w)),
                    fmaxf(fmaxf(f1.x, f1.y), fmaxf(f1.z, f1.w)));
#pragma unroll
    for (int o = 32; o > 0; o >>= 1) m = fmaxf(m, __shfl_down(m, o));
    if ((t & 63) == 0) sm[t >> 6] = m;
    __syncthreads();
    m = fmaxf(fmaxf(sm[0], sm[1]), fmaxf(sm[2], sm[3]));
    __syncthreads();

    f0.x = __expf(f0.x - m); f0.y = __expf(f0.y - m);
    f0.z = __expf(f0.z - m); f0.w = __expf(f0.w - m);
    f1.x = __expf(f1.x - m); f1.y = __expf(f1.y - m);
    f1.z = __expf(f1.z - m); f1.w = __expf(f1.w - m);

    float s = f0.x + f0.y + f0.z + f0.w + f1.x + f1.y + f1.z + f1.w;
#pragma unroll
    for (int o = 32; o > 0; o >>= 1) s += __shfl_down(s, o);
    if ((t & 63) == 0) sm[t >> 6] = s;
    __syncthreads();
    s = sm[0] + sm[1] + sm[2] + sm[3];
    const float inv = 1.0f / s;

    f0.x *= inv; f0.y *= inv; f0.z *= inv; f0.w *= inv;
    f1.x *= inv; f1.y *= inv; f1.z *= inv; f1.w *= inv;
    rp[t] = f0;
    rp[t + 256] = f1;
}

// ---------------------------------------------------------------------------
// PV: attn[b, s, h*64+dh] = sum_j P[bh, s, j] * v[bh, j, dh]
// grid (Mtiles=32, BH=32), block (16,16). N=64 (full head dim).
// ---------------------------------------------------------------------------
__global__ __launch_bounds__(256)
void pv_kernel(const float* __restrict__ scores, const float* __restrict__ v,
               float* __restrict__ attn)
{
    __shared__ float As[64][33];
    __shared__ float Bs[32][65];
    const int tx = threadIdx.x, ty = threadIdx.y;
    const int tid = ty * 16 + tx;
    const int bh = blockIdx.y;
    const int m0 = blockIdx.x * 64;
    const float* sb = scores + (size_t)bh * Ss * Ss;
    const float* vb = v + (size_t)bh * Ss * Dh;
    float acc[4][4] = {};
    for (int k0 = 0; k0 < Ss; k0 += 32) {
#pragma unroll
        for (int l = 0; l < 8; ++l) {
            int idx = l * 256 + tid;
            int r = idx >> 5, c = idx & 31;
            As[r][c] = sb[(size_t)(m0 + r) * Ss + k0 + c];
        }
#pragma unroll
        for (int l = 0; l < 8; ++l) {
            int idx = l * 256 + tid;
            int r = idx >> 6, c = idx & 63;
            Bs[r][c] = vb[(size_t)(k0 + r) * Dh + c];
        }
        __syncthreads();
#pragma unroll
        for (int kk = 0; kk < 32; ++kk) {
            float a[4], b[4];
#pragma unroll
            for (int i = 0; i < 4; ++i) a[i] = As[ty * 4 + i][kk];
#pragma unroll
            for (int j = 0; j < 4; ++j) b[j] = Bs[kk][tx * 4 + j];
#pragma unroll
            for (int i = 0; i < 4; ++i)
#pragma unroll
                for (int j = 0; j < 4; ++j)
                    acc[i][j] += a[i] * b[j];
        }
        __syncthreads();
    }
    const int b = bh >> 4, h = bh & 15;   // H = 16
#pragma unroll
    for (int i = 0; i < 4; ++i) {
        size_t srow = (size_t)b * Ss + (m0 + ty * 4 + i);
#pragma unroll
        for (int j = 0; j < 4; ++j)
            attn[srow * Dd + h * 64 + tx * 4 + j] = acc[i][j];
    }
}

// ---------------------------------------------------------------------------
// In-place LayerNorm over last dim (1024). One block per row, 4 elems/thread.
// ---------------------------------------------------------------------------
__global__ __launch_bounds__(256)
void ln_kernel(float* __restrict__ y, const float* __restrict__ gamma,
               const float* __restrict__ beta)
{
    __shared__ float sms[4];
    __shared__ float smss[4];
    const size_t row = blockIdx.x;
    float4* rp = (float4*)(y + row * Dd);
    const int t = threadIdx.x;
    float4 f = rp[t];
    float s  = f.x + f.y + f.z + f.w;
    float ss = f.x * f.x + f.y * f.y + f.z * f.z + f.w * f.w;
#pragma unroll
    for (int o = 32; o > 0; o >>= 1) {
        s  += __shfl_down(s, o);
        ss += __shfl_down(ss, o);
    }
    if ((t & 63) == 0) { sms[t >> 6] = s; smss[t >> 6] = ss; }
    __syncthreads();
    s  = sms[0] + sms[1] + sms[2] + sms[3];
    ss = smss[0] + smss[1] + smss[2] + smss[3];
    const float mean = s * (1.0f / Dd);
    const float var  = ss * (1.0f / Dd) - mean * mean;
    const float inv  = rsqrtf(var + EPSV);
    const float4 g  = ((const float4*)gamma)[t];
    const float4 be = ((const float4*)beta)[t];
    f.x = (f.x - mean) * inv * g.x + be.x;
    f.y = (f.y - mean) * inv * g.y + be.y;
    f.z = (f.z - mean) * inv * g.z + be.z;
    f.w = (f.w - mean) * inv * g.w + be.w;
    rp[t] = f;
}

extern "C" void kernel_launch(void* const* d_in, const int* in_sizes, int n_in,
                              void* d_out, int out_size, void* d_ws, size_t ws_size,
                              hipStream_t stream)
{
    const float* Q     = (const float*)d_in[0];
    const float* K     = (const float*)d_in[1];
    const float* V     = (const float*)d_in[2];
    const float* Wq    = (const float*)d_in[3];
    const float* bq    = (const float*)d_in[4];
    const float* Wk    = (const float*)d_in[5];
    const float* bk    = (const float*)d_in[6];
    const float* Wv    = (const float*)d_in[7];
    const float* bv    = (const float*)d_in[8];
    const float* Wo    = (const float*)d_in[9];
    const float* bo    = (const float*)d_in[10];
    const float* gamma = (const float*)d_in[11];
    const float* beta  = (const float*)d_in[12];

    float* outY   = (float*)d_out;                       // [B,S,D] = 4194304
    float* scores = outY + (size_t)BS * Dd;              // [B,H,S,S] = 134217728

    float* ws   = (float*)d_ws;                          // needs 64 MB
    float* qw   = ws;                                    // [B,H,S,Dh]
    float* kw   = ws + QKV;
    float* vw   = ws + 2 * QKV;
    float* attn = ws + 3 * QKV;                          // [B,S,D]

    dim3 blk(16, 16);
    proj_qkv_kernel<<<dim3(16, 64), blk, 0, stream>>>(Q, Wq, bq, qw);
    proj_qkv_kernel<<<dim3(16, 64), blk, 0, stream>>>(K, Wk, bk, kw);
    proj_qkv_kernel<<<dim3(16, 64), blk, 0, stream>>>(V, Wv, bv, vw);
    scores_kernel<<<dim3(32, 32, 32), blk, 0, stream>>>(qw, kw, scores);
    softmax_kernel<<<dim3(65536), dim3(256), 0, stream>>>(scores);
    pv_kernel<<<dim3(32, 32), blk, 0, stream>>>(scores, vw, attn);
    outproj_kernel<<<dim3(16, 64), blk, 0, stream>>>(attn, Wo, bo, Q, outY);
    ln_kernel<<<dim3(4096), dim3(256), 0, stream>>>(outY, gamma, beta);
}